// Round 2
// baseline (185.021 us; speedup 1.0000x reference)
//
#include <hip/hip_runtime.h>
#include <hip/hip_bf16.h>

// Flash-attention forward, block-causal (packed varlen docs).
// Inputs/outputs fp32 in HBM; bf16 MFMA compute internally.
// B=1, H=8, D=128; 1 block = (head, 64-row Q tile); 4 waves x 16 Q-rows.

#define HD 128
#define BR 64
#define BC 64
#define KSTRIDE (HD + 8)   // LDS row stride (bf16 elems) for K/V tiles
#define PSTRIDE (BC + 8)   // LDS row stride for P tiles

typedef __attribute__((ext_vector_type(8))) short short8;
typedef __attribute__((ext_vector_type(4))) short short4v;
typedef __attribute__((ext_vector_type(4))) float floatx4;

__device__ inline short f2bf(float f) {
    __hip_bfloat16 b = __float2bfloat16(f);
    return *reinterpret_cast<short*>(&b);
}

__global__ __launch_bounds__(256) void fa_fwd(
    const float* __restrict__ Q,
    const float* __restrict__ K,
    const float* __restrict__ V,
    const int* __restrict__ cu_seqlens, int n_cu,
    float* __restrict__ O,
    int S)
{
    __shared__ alignas(16) __hip_bfloat16 sK[BC * KSTRIDE];
    __shared__ alignas(16) __hip_bfloat16 sV[BC * KSTRIDE];
    __shared__ alignas(16) __hip_bfloat16 sP[4 * 16 * PSTRIDE];

    const int tid  = threadIdx.x;
    const int wave = tid >> 6;
    const int lane = tid & 63;
    const int quad = lane >> 4;    // 0..3
    const int l16  = lane & 15;

    const int nqb = S / BR;
    const int h   = blockIdx.x / nqb;
    const int qb  = blockIdx.x % nqb;
    const int q0  = qb * BR;
    const int qw  = q0 + wave * 16;

    const size_t hoff = (size_t)h * S * HD;
    const float* Qh = Q + hoff;
    const float* Kh = K + hoff;
    const float* Vh = V + hoff;
    float*       Oh = O + hoff;

    // ---- per-row doc starts ----
    int doc_start[4];
    for (int r = 0; r < 4; ++r) {
        int q = qw + quad * 4 + r;
        int dsr = 0;
        for (int i = 0; i < n_cu; ++i) {
            int c = cu_seqlens[i];
            if (c <= q) dsr = c;
        }
        doc_start[r] = dsr;
    }
    int blk_doc_start = 0;
    for (int i = 0; i < n_cu; ++i) {
        int c = cu_seqlens[i];
        if (c <= q0) blk_doc_start = c;
    }
    const int k_begin = blk_doc_start & ~(BC - 1);
    const int k_end   = q0 + BR - 1;
    const int ntiles  = (k_end - k_begin) / BC + 1;   // block-uniform

    // ---- Q fragments: A[m=l16][k = t*32 + quad*8 + j], fp32->bf16 ----
    short8 aq[4];
    {
        const float* qp = Qh + (size_t)(qw + l16) * HD + quad * 8;
        #pragma unroll
        for (int t = 0; t < 4; ++t) {
            float4 a0 = *(const float4*)(qp + t * 32);
            float4 a1 = *(const float4*)(qp + t * 32 + 4);
            short8 a;
            a[0] = f2bf(a0.x); a[1] = f2bf(a0.y); a[2] = f2bf(a0.z); a[3] = f2bf(a0.w);
            a[4] = f2bf(a1.x); a[5] = f2bf(a1.y); a[6] = f2bf(a1.z); a[7] = f2bf(a1.w);
            aq[t] = a;
        }
    }

    floatx4 oacc[8];
    #pragma unroll
    for (int dt = 0; dt < 8; ++dt) oacc[dt] = (floatx4){0.f, 0.f, 0.f, 0.f};
    float m_r[4], l_r[4];
    #pragma unroll
    for (int r = 0; r < 4; ++r) { m_r[r] = -1e30f; l_r[r] = 0.f; }

    const float sl = 0.08838834764831845f * 1.4426950408889634f;  // scale * log2(e)

    __hip_bfloat16* pbuf = &sP[wave * 16 * PSTRIDE];

    for (int it = 0; it < ntiles; ++it) {
        const int kt = k_begin + it * BC;

        // ---- stage K,V tile [64 x 128] fp32 -> bf16 LDS ----
        #pragma unroll
        for (int p = 0; p < 8; ++p) {
            const int idx4 = p * 256 + tid;      // float4 index in 64x128 tile
            const int row  = idx4 >> 5;          // 32 float4 per row
            const int c    = (idx4 & 31) * 4;
            const size_t g = (size_t)(kt + row) * HD + c;
            float4 fk = *(const float4*)(Kh + g);
            float4 fv = *(const float4*)(Vh + g);
            short4v hk, hv;
            hk[0] = f2bf(fk.x); hk[1] = f2bf(fk.y); hk[2] = f2bf(fk.z); hk[3] = f2bf(fk.w);
            hv[0] = f2bf(fv.x); hv[1] = f2bf(fv.y); hv[2] = f2bf(fv.z); hv[3] = f2bf(fv.w);
            *(short4v*)(&sK[row * KSTRIDE + c]) = hk;
            *(short4v*)(&sV[row * KSTRIDE + c]) = hv;
        }
        __syncthreads();

        // ---- S = Q K^T : 16 rows x 64 keys ----
        floatx4 sc[4];
        #pragma unroll
        for (int ct = 0; ct < 4; ++ct) {
            floatx4 c = (floatx4){0.f, 0.f, 0.f, 0.f};
            #pragma unroll
            for (int ks = 0; ks < 4; ++ks) {
                short8 b = *(const short8*)(&sK[(ct * 16 + l16) * KSTRIDE + ks * 32 + quad * 8]);
                c = __builtin_amdgcn_mfma_f32_16x16x32_bf16(aq[ks], b, c, 0, 0, 0);
            }
            sc[ct] = c;
        }

        // ---- scale + mask (C layout: row = quad*4+r, col = ct*16+l16) ----
        #pragma unroll
        for (int ct = 0; ct < 4; ++ct) {
            const int key = kt + ct * 16 + l16;
            #pragma unroll
            for (int r = 0; r < 4; ++r) {
                const int q = qw + quad * 4 + r;
                const bool valid = (key <= q) && (key >= doc_start[r]);
                float s = sc[ct][r] * sl;
                sc[ct][r] = valid ? s : -1e30f;
            }
        }

        // ---- online softmax ----
        #pragma unroll
        for (int r = 0; r < 4; ++r) {
            float mx = fmaxf(fmaxf(sc[0][r], sc[1][r]), fmaxf(sc[2][r], sc[3][r]));
            #pragma unroll
            for (int off = 1; off < 16; off <<= 1)
                mx = fmaxf(mx, __shfl_xor(mx, off, 64));
            const float mnew = fmaxf(m_r[r], mx);
            const float al = exp2f(m_r[r] - mnew);
            float psum = 0.f;
            #pragma unroll
            for (int ct = 0; ct < 4; ++ct) {
                const float s = sc[ct][r];
                const float p = (s > -1e29f) ? exp2f(s - mnew) : 0.f;
                sc[ct][r] = p;
                psum += p;
            }
            #pragma unroll
            for (int off = 1; off < 16; off <<= 1)
                psum += __shfl_xor(psum, off, 64);
            l_r[r] = l_r[r] * al + psum;
            m_r[r] = mnew;
            #pragma unroll
            for (int dt = 0; dt < 8; ++dt) oacc[dt][r] *= al;
        }

        // ---- P (C layout) -> LDS -> A layout ----
        #pragma unroll
        for (int ct = 0; ct < 4; ++ct)
            #pragma unroll
            for (int r = 0; r < 4; ++r)
                pbuf[(quad * 4 + r) * PSTRIDE + ct * 16 + l16] = __float2bfloat16(sc[ct][r]);
        __syncthreads();

        // ---- O += P V ----
        #pragma unroll
        for (int ks = 0; ks < 2; ++ks) {
            short8 ap = *(const short8*)(&pbuf[l16 * PSTRIDE + ks * 32 + quad * 8]);
            #pragma unroll
            for (int dt = 0; dt < 8; ++dt) {
                short8 bv;
                #pragma unroll
                for (int j = 0; j < 8; ++j)
                    bv[j] = *(const short*)&sV[(ks * 32 + quad * 8 + j) * KSTRIDE + dt * 16 + l16];
                oacc[dt] = __builtin_amdgcn_mfma_f32_16x16x32_bf16(ap, bv, oacc[dt], 0, 0, 0);
            }
        }
        __syncthreads();
    }

    // ---- epilogue: normalize, store fp32 ----
    #pragma unroll
    for (int r = 0; r < 4; ++r) {
        const float inv = 1.0f / l_r[r];
        float* op = Oh + (size_t)(qw + quad * 4 + r) * HD;
        #pragma unroll
        for (int dt = 0; dt < 8; ++dt)
            op[dt * 16 + l16] = oacc[dt][r] * inv;
    }
}

extern "C" void kernel_launch(void* const* d_in, const int* in_sizes, int n_in,
                              void* d_out, int out_size, void* d_ws, size_t ws_size,
                              hipStream_t stream) {
    const float* q = (const float*)d_in[0];
    const float* k = (const float*)d_in[1];
    const float* v = (const float*)d_in[2];
    const int* cu = (const int*)d_in[3];
    const int n_cu = in_sizes[3];
    const int H = 8;
    const int S = in_sizes[0] / (H * HD);   // B=1
    float* out = (float*)d_out;

    dim3 grid(H * (S / BR));
    dim3 block(256);
    fa_fwd<<<grid, block, 0, stream>>>(q, k, v, cu, n_cu, out, S);
}